// Round 6
// baseline (110.156 us; speedup 1.0000x reference)
//
#include <hip/hip_runtime.h>

#define NLEV 127.0f
#define QEPS 1e-8f
#define GRID 512

// ws layout (floats):
// [0]            barrier counter (uint, zeroed by hipMemsetAsync each call)
// [32..32+GRID)  per-block |x| partial maxima

__device__ __forceinline__ float max4(float4 v) {
    return fmaxf(fmaxf(fabsf(v.x), fabsf(v.y)), fmaxf(fabsf(v.z), fabsf(v.w)));
}
__device__ __forceinline__ float clipr(float v) {
    return fminf(fmaxf(rintf(v), -NLEV), NLEV);
}

__global__ void __launch_bounds__(256, 2) k_fused(
        const float4* __restrict__ x4,
        const float* __restrict__ w0, const float* __restrict__ b0,
        const float* __restrict__ w2, const float* __restrict__ b2,
        const float* __restrict__ w4, const float* __restrict__ b4,
        const float* __restrict__ w6, const float* __restrict__ b6,
        float* __restrict__ ws, float4* __restrict__ out4,
        int n4, int nTiles, int B) {
    __shared__ float T[64][16], Tn[64][16];
    __shared__ float cc[64], cn[64], sfv[64], bi[64];
    __shared__ float Wq[64 * 64];
    __shared__ unsigned rmax[64];
    __shared__ float red[4];
    __shared__ float s_sh;
    __shared__ __align__(16) float ostage[640];
    const int t = threadIdx.x;
    unsigned* ctr = (unsigned*)ws;

    // ================= phase A: per-block |x| absmax =================
    {
        const int tid = blockIdx.x * 256 + t;
        const int stride = GRID * 256;
        float m[8];
        #pragma unroll
        for (int k = 0; k < 8; ++k) m[k] = 0.f;
        int i = tid;
        for (; i + 7 * stride < n4; i += 8 * stride) {
            #pragma unroll
            for (int k = 0; k < 8; ++k) m[k] = fmaxf(m[k], max4(x4[i + k * stride]));
        }
        for (; i < n4; i += stride) m[0] = fmaxf(m[0], max4(x4[i]));
        float mm = fmaxf(fmaxf(fmaxf(m[0], m[1]), fmaxf(m[2], m[3])),
                         fmaxf(fmaxf(m[4], m[5]), fmaxf(m[6], m[7])));
        #pragma unroll
        for (int off = 32; off > 0; off >>= 1)
            mm = fmaxf(mm, __shfl_down(mm, off, 64));
        if ((t & 63) == 0) red[t >> 6] = mm;
        __syncthreads();
        if (t == 0) {
            float pv = fmaxf(fmaxf(red[0], red[1]), fmaxf(red[2], red[3]));
            __hip_atomic_store(&ws[32 + blockIdx.x], pv,
                               __ATOMIC_RELEASE, __HIP_MEMORY_SCOPE_AGENT);
            __hip_atomic_fetch_add(ctr, 1u, __ATOMIC_ACQ_REL, __HIP_MEMORY_SCOPE_AGENT);
            // ---- device-wide barrier: all GRID blocks are co-resident
            // (grid = 2 blocks/CU, __launch_bounds__(256,2) guarantees fit) ----
            while (__hip_atomic_load(ctr, __ATOMIC_ACQUIRE, __HIP_MEMORY_SCOPE_AGENT)
                   < (unsigned)GRID) {
                __builtin_amdgcn_s_sleep(2);
            }
        }
        __syncthreads();
    }

    // ================= phase B: redundant per-block compose =================
    {
        float pm = 0.f;
        for (int i = t; i < GRID; i += 256)
            pm = fmaxf(pm, __hip_atomic_load(&ws[32 + i], __ATOMIC_RELAXED,
                                             __HIP_MEMORY_SCOPE_AGENT));
        #pragma unroll
        for (int off = 32; off > 0; off >>= 1)
            pm = fmaxf(pm, __shfl_down(pm, off, 64));
        if ((t & 63) == 0) red[t >> 6] = pm;
        __syncthreads();
        if (t == 0) {
            float am = fmaxf(fmaxf(red[0], red[1]), fmaxf(red[2], red[3]));
            s_sh = fmaxf(am / NLEV, QEPS);
        }
        for (int i = t; i < 64 * 16; i += 256) {
            int r = i >> 4, ci = i & 15;
            T[r][ci] = (r == ci) ? 1.f : 0.f;
        }
        if (t < 64) cc[t] = 0.f;
        __syncthreads();
        const float s = s_sh;

        const float* Ws[4] = {w0, w2, w4, w6};
        const float* Bs[4] = {b0, b2, b4, b6};
        const int    Od[4] = {64, 32, 32, 5};
        const int    Fd[4] = {16, 64, 32, 32};

        for (int L = 0; L < 4; ++L) {
            const int O = Od[L], F = Fd[L];
            const float* W = Ws[L];
            const float* Bb = Bs[L];
            if (t < 64) rmax[t] = 0u;
            __syncthreads();
            const int nf4 = O * F / 4, f4row = F / 4;
            for (int i = t; i < nf4; i += 256) {
                float4 wv = ((const float4*)W)[i];
                atomicMax(&rmax[i / f4row], __float_as_uint(max4(wv)));
            }
            __syncthreads();
            if (t < O) {
                float sf = fmaxf(__uint_as_float(rmax[t]) / NLEV, QEPS);
                sfv[t] = sf;
                bi[t]  = clipr(Bb[t] / (sf * s));
            }
            __syncthreads();
            for (int i = t; i < O * F; i += 256)
                Wq[i] = clipr(W[i] / sfv[i / F]);
            __syncthreads();
            for (int i = t; i < O * 16; i += 256) {
                int o = i >> 4, col = i & 15;
                float acc = 0.f;
                #pragma unroll 8
                for (int j = 0; j < F; ++j) acc += Wq[o * F + j] * T[j][col];
                Tn[o][col] = acc * sfv[o];
            }
            if (t < O) {
                float acc = bi[t];
                #pragma unroll 8
                for (int j = 0; j < F; ++j) acc += Wq[t * F + j] * cc[j];
                cn[t] = acc * sfv[t];
            }
            __syncthreads();
            for (int i = t; i < O * 16; i += 256) T[i >> 4][i & 15] = Tn[i >> 4][i & 15];
            if (t < O) cc[t] = cn[t];
            __syncthreads();
        }
        // fold final *s into T rows 0..4 and cc[0..4]
        for (int i = t; i < 80; i += 256) T[i >> 4][i & 15] *= s;
        if (t < 5) cc[t] *= s;
        __syncthreads();
    }

    // ================= phase C: streaming main pass (x L3-hot) =================
    const float inv_s = 1.0f / s_sh;
    const int v = t & 3;
    const int lrow = t >> 2;
    float Mreg[5][4], cadd[5];
    #pragma unroll
    for (int oo = 0; oo < 5; ++oo) {
        cadd[oo] = cc[oo];
        #pragma unroll
        for (int j = 0; j < 4; ++j) Mreg[oo][j] = T[oo][v * 4 + j];
    }
    __syncthreads();

    int parity = 0;
    int tile = blockIdx.x;
    float4 xv = make_float4(0.f, 0.f, 0.f, 0.f);
    if (tile < nTiles) xv = x4[(size_t)tile * 256 + t];
    for (; tile < nTiles; tile += GRID, parity ^= 1) {
        const int nt = tile + GRID;
        float4 xn = make_float4(0.f, 0.f, 0.f, 0.f);
        if (nt < nTiles) xn = x4[(size_t)nt * 256 + t];

        float q0 = fminf(fmaxf(rintf(xv.x * inv_s), -NLEV), NLEV);
        float q1 = fminf(fmaxf(rintf(xv.y * inv_s), -NLEV), NLEV);
        float q2 = fminf(fmaxf(rintf(xv.z * inv_s), -NLEV), NLEV);
        float q3 = fminf(fmaxf(rintf(xv.w * inv_s), -NLEV), NLEV);

        float* buf = ostage + (parity ? 320 : 0);
        float p[5];
        #pragma unroll
        for (int oo = 0; oo < 5; ++oo) {
            float acc = fmaf(q0, Mreg[oo][0],
                        fmaf(q1, Mreg[oo][1],
                        fmaf(q2, Mreg[oo][2], q3 * Mreg[oo][3])));
            acc += __shfl_xor(acc, 1, 64);
            acc += __shfl_xor(acc, 2, 64);
            p[oo] = acc;
        }
        if (v == 0) {
            #pragma unroll
            for (int oo = 0; oo < 5; ++oo) buf[lrow * 5 + oo] = p[oo] + cadd[oo];
        }
        __syncthreads();
        if (t < 80) out4[(size_t)tile * 80 + t] = ((const float4*)buf)[t];
        xv = xn;
    }

    // tail rows (B not a multiple of 64) — block 0, scalar path
    const int tailStart = nTiles * 64;
    if (blockIdx.x == 0 && tailStart < B) {
        for (int r = tailStart + t; r < B; r += 256) {
            const float* xr = (const float*)x4 + (size_t)r * 16;
            float q[16];
            #pragma unroll
            for (int i = 0; i < 16; ++i)
                q[i] = fminf(fmaxf(rintf(xr[i] * inv_s), -NLEV), NLEV);
            #pragma unroll
            for (int oo = 0; oo < 5; ++oo) {
                float acc = cadd[oo];
                // cadd/Mreg only cover this lane's v-slice; recompute from LDS
                acc = cc[oo];
                for (int i = 0; i < 16; ++i) acc = fmaf(q[i], T[oo][i], acc);
                ((float*)out4)[(size_t)r * 5 + oo] = acc;
            }
        }
    }
}

extern "C" void kernel_launch(void* const* d_in, const int* in_sizes, int n_in,
                              void* d_out, int out_size, void* d_ws, size_t ws_size,
                              hipStream_t stream) {
    const float* x  = (const float*)d_in[0];
    const float* w0 = (const float*)d_in[1];
    const float* b0 = (const float*)d_in[2];
    const float* w2 = (const float*)d_in[3];
    const float* b2 = (const float*)d_in[4];
    const float* w4 = (const float*)d_in[5];
    const float* b4 = (const float*)d_in[6];
    const float* w6 = (const float*)d_in[7];
    const float* b6 = (const float*)d_in[8];
    float* ws = (float*)d_ws;

    const int B  = in_sizes[0] / 16;
    const int n4 = B * 4;        // float4 elements of x
    const int nTiles = B / 64;   // 64-row tiles

    // zero the barrier counter (stream-ordered, graph-capture legal)
    hipMemsetAsync(ws, 0, sizeof(unsigned), stream);
    k_fused<<<GRID, 256, 0, stream>>>((const float4*)x,
                                      w0, b0, w2, b2, w4, b4, w6, b6,
                                      ws, (float4*)d_out, n4, nTiles, B);
}

// Round 7
// 82.817 us; speedup vs baseline: 1.3301x; 1.3301x over previous
//
#include <hip/hip_runtime.h>

#define NLEV 127.0f
#define QEPS 1e-8f
#define NPART 2048

// ws layout (floats):
// [0..2047]      per-block |x| partial maxima
// [2048..2127]   T_lin[5][16]  (s-independent composite linear map)
// [2128..2260]   bpre[133] = b/w_sf, [l0:64 | l1:32 | l2:32 | l3:5]
// [2304..2968]   C[5][133] row-major bias-coefficient matrix (incl. L3 diag)
#define WS_PART 0
#define WS_TLIN 2048
#define WS_BPRE 2128
#define WS_C    2304

__device__ __forceinline__ float max4(float4 v) {
    return fmaxf(fmaxf(fabsf(v.x), fabsf(v.y)), fmaxf(fabsf(v.z), fabsf(v.w)));
}
__device__ __forceinline__ float clipr(float v) {
    return fminf(fmaxf(rintf(v), -NLEV), NLEV);
}

// ---- k1: blocks 0..NPART-1 scan |x|; block NPART composes s-independent parts ----
__global__ void __launch_bounds__(256) k1_absmax_compose(
        const float4* __restrict__ x4,
        const float* __restrict__ w0, const float* __restrict__ b0,
        const float* __restrict__ w2, const float* __restrict__ b2,
        const float* __restrict__ w4, const float* __restrict__ b4,
        const float* __restrict__ w6, const float* __restrict__ b6,
        float* __restrict__ ws, int n4) {
    const int t = threadIdx.x;

    if (blockIdx.x < NPART) {
        const int tid = blockIdx.x * 256 + t;
        const int stride = NPART * 256;
        float m[8];
        #pragma unroll
        for (int k = 0; k < 8; ++k) m[k] = 0.f;
        int i = tid;
        for (; i + 7 * stride < n4; i += 8 * stride) {
            #pragma unroll
            for (int k = 0; k < 8; ++k) m[k] = fmaxf(m[k], max4(x4[i + k * stride]));
        }
        for (; i < n4; i += stride) m[0] = fmaxf(m[0], max4(x4[i]));
        float mm = fmaxf(fmaxf(fmaxf(m[0], m[1]), fmaxf(m[2], m[3])),
                         fmaxf(fmaxf(m[4], m[5]), fmaxf(m[6], m[7])));
        #pragma unroll
        for (int off = 32; off > 0; off >>= 1)
            mm = fmaxf(mm, __shfl_down(mm, off, 64));
        __shared__ float sm[4];
        if ((t & 63) == 0) sm[t >> 6] = mm;
        __syncthreads();
        if (t == 0)
            ws[WS_PART + blockIdx.x] = fmaxf(fmaxf(sm[0], sm[1]), fmaxf(sm[2], sm[3]));
        return;
    }

    // ---- compose block (entirely s-independent), layers processed 3 -> 0 ----
    __shared__ float Wq[2048];          // max O*F = 32*64
    __shared__ float Rm[5 * 64], Rn[5 * 64], Cm[5 * 64];
    __shared__ float sfv[64];
    __shared__ unsigned rmax[64];

    const float* Wl[4] = {w0, w2, w4, w6};
    const float* Bl[4] = {b0, b2, b4, b6};
    const int Ol[4] = {64, 32, 32, 5};
    const int Fl[4] = {16, 64, 32, 32};
    const int bpre_off[4] = {0, 64, 96, 128};
    const int cs_base[4]  = {0, 64, 96, 128};

    for (int L = 3; L >= 0; --L) {
        const int O = Ol[L], F = Fl[L];
        const float* W = Wl[L];
        const float* Bb = Bl[L];
        if (t < 64) rmax[t] = 0u;
        __syncthreads();
        const int nf4 = O * F / 4, f4row = F / 4;
        for (int i = t; i < nf4; i += 256) {
            float4 wv = ((const float4*)W)[i];
            atomicMax(&rmax[i / f4row], __float_as_uint(max4(wv)));
        }
        __syncthreads();
        if (t < O) {
            float sf = fmaxf(__uint_as_float(rmax[t]) / NLEV, QEPS);
            sfv[t] = sf;
            ws[WS_BPRE + bpre_off[L] + t] = Bb[t] / sf;
        }
        __syncthreads();
        for (int i = t; i < O * F; i += 256)
            Wq[i] = clipr(W[i] / sfv[i / F]);
        __syncthreads();

        if (L == 3) {
            // Rm = D3 * Wq3  (5 x 32);  C[.][128..132] = D3 diagonal
            for (int i = t; i < 5 * F; i += 256) Rm[i] = sfv[i / F] * Wq[i];
            if (t < 25) {
                int oo = t / 5, k = t % 5;
                ws[WS_C + oo * 133 + cs_base[3] + k] = (k == oo) ? sfv[oo] : 0.f;
            }
            __syncthreads();
        } else {
            // Cm = Rm * D_L  (this layer's bias coefficient block)
            for (int i = t; i < 5 * O; i += 256) {
                int r = i / O, c0 = i % O;
                float v = Rm[r * O + c0] * sfv[c0];
                Cm[i] = v;
                ws[WS_C + r * 133 + cs_base[L] + c0] = v;
            }
            __syncthreads();
            // Rn = Cm (5xO) * Wq (OxF)
            for (int i = t; i < 5 * F; i += 256) {
                int r = i / F, c0 = i % F;
                float acc = 0.f;
                #pragma unroll 8
                for (int j = 0; j < O; ++j) acc += Cm[r * O + j] * Wq[j * F + c0];
                Rn[i] = acc;
            }
            __syncthreads();
            if (L == 0) {
                for (int i = t; i < 80; i += 256) ws[WS_TLIN + i] = Rn[i];
            } else {
                for (int i = t; i < 5 * F; i += 256) Rm[i] = Rn[i];
                __syncthreads();
            }
        }
    }
}

// ---- k2: per-block finalize prologue (redundant, overlapped) + streaming main ----
__global__ void __launch_bounds__(256) k2_main(const float4* __restrict__ x4,
                                               const float* __restrict__ ws,
                                               float4* __restrict__ out4,
                                               int nTiles, int B) {
    __shared__ __align__(16) float ostage[640];
    __shared__ float bi[133];
    __shared__ float csh[5];
    __shared__ float Msh[80];
    __shared__ float red[4];
    __shared__ float s_sh;
    const int t = threadIdx.x;

    // s from partials
    float pm = 0.f;
    for (int i = t; i < NPART; i += 256) pm = fmaxf(pm, ws[WS_PART + i]);
    #pragma unroll
    for (int off = 32; off > 0; off >>= 1)
        pm = fmaxf(pm, __shfl_down(pm, off, 64));
    if ((t & 63) == 0) red[t >> 6] = pm;
    __syncthreads();
    if (t == 0) {
        float am = fmaxf(fmaxf(red[0], red[1]), fmaxf(red[2], red[3]));
        s_sh = fmaxf(am / NLEV, QEPS);
    }
    __syncthreads();
    const float s = s_sh;
    const float inv_s = 1.0f / s;

    // bi = clipr(bpre * inv_s)
    for (int i = t; i < 133; i += 256) bi[i] = clipr(ws[WS_BPRE + i] * inv_s);
    for (int i = t; i < 80; i += 256)  Msh[i] = ws[WS_TLIN + i] * s;
    __syncthreads();
    // c[oo] = s * dot(C[oo][:], bi)   — 5 groups of 32 lanes
    if (t < 160) {
        int oo = t >> 5, lane = t & 31;
        float acc = 0.f;
        for (int j = lane; j < 133; j += 32) acc += ws[WS_C + oo * 133 + j] * bi[j];
        #pragma unroll
        for (int off = 16; off > 0; off >>= 1)
            acc += __shfl_xor(acc, off, 32);
        if (lane == 0) csh[oo] = acc * s;
    }
    __syncthreads();

    const int v = t & 3;
    const int lrow = t >> 2;
    float Mreg[5][4], cadd[5];
    #pragma unroll
    for (int oo = 0; oo < 5; ++oo) {
        cadd[oo] = csh[oo];
        #pragma unroll
        for (int j = 0; j < 4; ++j) Mreg[oo][j] = Msh[oo * 16 + v * 4 + j];
    }

    // streaming main loop (R5 structure)
    int parity = 0;
    int tile = blockIdx.x;
    float4 xv = make_float4(0.f, 0.f, 0.f, 0.f);
    if (tile < nTiles) xv = x4[(size_t)tile * 256 + t];
    for (; tile < nTiles; tile += gridDim.x, parity ^= 1) {
        const int nt = tile + gridDim.x;
        float4 xn = make_float4(0.f, 0.f, 0.f, 0.f);
        if (nt < nTiles) xn = x4[(size_t)nt * 256 + t];

        float q0 = fminf(fmaxf(rintf(xv.x * inv_s), -NLEV), NLEV);
        float q1 = fminf(fmaxf(rintf(xv.y * inv_s), -NLEV), NLEV);
        float q2 = fminf(fmaxf(rintf(xv.z * inv_s), -NLEV), NLEV);
        float q3 = fminf(fmaxf(rintf(xv.w * inv_s), -NLEV), NLEV);

        float* buf = ostage + (parity ? 320 : 0);
        float p[5];
        #pragma unroll
        for (int oo = 0; oo < 5; ++oo) {
            float acc = fmaf(q0, Mreg[oo][0],
                        fmaf(q1, Mreg[oo][1],
                        fmaf(q2, Mreg[oo][2], q3 * Mreg[oo][3])));
            acc += __shfl_xor(acc, 1, 64);
            acc += __shfl_xor(acc, 2, 64);
            p[oo] = acc;
        }
        if (v == 0) {
            #pragma unroll
            for (int oo = 0; oo < 5; ++oo) buf[lrow * 5 + oo] = p[oo] + cadd[oo];
        }
        __syncthreads();
        if (t < 80) out4[(size_t)tile * 80 + t] = ((const float4*)buf)[t];
        xv = xn;
    }

    // tail rows (B not a multiple of 64) — block 0, scalar path
    const int tailStart = nTiles * 64;
    if (blockIdx.x == 0 && tailStart < B) {
        for (int r = tailStart + t; r < B; r += 256) {
            const float* xr = (const float*)x4 + (size_t)r * 16;
            float q[16];
            #pragma unroll
            for (int i = 0; i < 16; ++i)
                q[i] = fminf(fmaxf(rintf(xr[i] * inv_s), -NLEV), NLEV);
            #pragma unroll
            for (int oo = 0; oo < 5; ++oo) {
                float acc = csh[oo];
                for (int i = 0; i < 16; ++i) acc = fmaf(q[i], Msh[oo * 16 + i], acc);
                ((float*)out4)[(size_t)r * 5 + oo] = acc;
            }
        }
    }
}

extern "C" void kernel_launch(void* const* d_in, const int* in_sizes, int n_in,
                              void* d_out, int out_size, void* d_ws, size_t ws_size,
                              hipStream_t stream) {
    const float* x  = (const float*)d_in[0];
    const float* w0 = (const float*)d_in[1];
    const float* b0 = (const float*)d_in[2];
    const float* w2 = (const float*)d_in[3];
    const float* b2 = (const float*)d_in[4];
    const float* w4 = (const float*)d_in[5];
    const float* b4 = (const float*)d_in[6];
    const float* w6 = (const float*)d_in[7];
    const float* b6 = (const float*)d_in[8];
    float* ws = (float*)d_ws;

    const int B  = in_sizes[0] / 16;
    const int n4 = B * 4;        // float4 elements of x
    const int nTiles = B / 64;   // 64-row tiles

    k1_absmax_compose<<<NPART + 1, 256, 0, stream>>>(
        (const float4*)x, w0, b0, w2, b2, w4, b4, w6, b6, ws, n4);
    k2_main<<<2048, 256, 0, stream>>>((const float4*)x, ws, (float4*)d_out,
                                      nTiles, B);
}

// Round 8
// 58.886 us; speedup vs baseline: 1.8706x; 1.4064x over previous
//
#include <hip/hip_runtime.h>

#define NLEV 127.0f
#define QEPS 1e-8f
#define SCAN_BLOCKS 2048

// ws layout (floats):
// [0]           absmax bits (uint atomicMax target; zeroed via hipMemsetAsync)
// [64..143]     T_lin[5][16]  (s-independent composite linear map)
// [160..292]    bpre[133] = b/w_sf, [l0:64 | l1:32 | l2:32 | l3:5]
// [304..968]    C[5][133] row-major bias-coefficient matrix (incl. L3 diag)
// [1024]        inv_s
// [1025..1104]  M[5][16] (pre-scaled by s)
// [1105..1109]  c[5]
#define WS_ABS  0
#define WS_TLIN 64
#define WS_BPRE 160
#define WS_C    304
#define WS_FIN  1024

__device__ __forceinline__ float max4(float4 v) {
    return fmaxf(fmaxf(fabsf(v.x), fabsf(v.y)), fmaxf(fabsf(v.z), fabsf(v.w)));
}
__device__ __forceinline__ float clipr(float v) {
    return fminf(fmaxf(rintf(v), -NLEV), NLEV);
}

// ---- k1: blocks 0..SCAN_BLOCKS-1 scan |x|; block SCAN_BLOCKS composes ----
__global__ void __launch_bounds__(256) k1_absmax_compose(
        const float4* __restrict__ x4,
        const float* __restrict__ w0, const float* __restrict__ b0,
        const float* __restrict__ w2, const float* __restrict__ b2,
        const float* __restrict__ w4, const float* __restrict__ b4,
        const float* __restrict__ w6, const float* __restrict__ b6,
        float* __restrict__ ws, int n4) {
    const int t = threadIdx.x;

    if (blockIdx.x < SCAN_BLOCKS) {
        const int tid = blockIdx.x * 256 + t;
        const int stride = SCAN_BLOCKS * 256;
        float m[8];
        #pragma unroll
        for (int k = 0; k < 8; ++k) m[k] = 0.f;
        int i = tid;
        for (; i + 7 * stride < n4; i += 8 * stride) {
            #pragma unroll
            for (int k = 0; k < 8; ++k) m[k] = fmaxf(m[k], max4(x4[i + k * stride]));
        }
        for (; i < n4; i += stride) m[0] = fmaxf(m[0], max4(x4[i]));
        float mm = fmaxf(fmaxf(fmaxf(m[0], m[1]), fmaxf(m[2], m[3])),
                         fmaxf(fmaxf(m[4], m[5]), fmaxf(m[6], m[7])));
        #pragma unroll
        for (int off = 32; off > 0; off >>= 1)
            mm = fmaxf(mm, __shfl_down(mm, off, 64));
        __shared__ float sm[4];
        if ((t & 63) == 0) sm[t >> 6] = mm;
        __syncthreads();
        if (t == 0) {
            float pv = fmaxf(fmaxf(sm[0], sm[1]), fmaxf(sm[2], sm[3]));
            atomicMax((unsigned*)&ws[WS_ABS], __float_as_uint(pv));  // |x|>=0: uint order == float order
        }
        return;
    }

    // ---- compose block (entirely s-independent), layers processed 3 -> 0 ----
    __shared__ float Wq[2048];          // max O*F = 32*64
    __shared__ float Rm[5 * 64], Rn[5 * 64], Cm[5 * 64];
    __shared__ float sfv[64];
    __shared__ unsigned rmax[64];

    const float* Wl[4] = {w0, w2, w4, w6};
    const float* Bl[4] = {b0, b2, b4, b6};
    const int Ol[4] = {64, 32, 32, 5};
    const int Fl[4] = {16, 64, 32, 32};
    const int bpre_off[4] = {0, 64, 96, 128};
    const int cs_base[4]  = {0, 64, 96, 128};

    for (int L = 3; L >= 0; --L) {
        const int O = Ol[L], F = Fl[L];
        const float* W = Wl[L];
        const float* Bb = Bl[L];
        if (t < 64) rmax[t] = 0u;
        __syncthreads();
        const int nf4 = O * F / 4, f4row = F / 4;
        for (int i = t; i < nf4; i += 256) {
            float4 wv = ((const float4*)W)[i];
            atomicMax(&rmax[i / f4row], __float_as_uint(max4(wv)));
        }
        __syncthreads();
        if (t < O) {
            float sf = fmaxf(__uint_as_float(rmax[t]) / NLEV, QEPS);
            sfv[t] = sf;
            ws[WS_BPRE + bpre_off[L] + t] = Bb[t] / sf;
        }
        __syncthreads();
        for (int i = t; i < O * F; i += 256)
            Wq[i] = clipr(W[i] / sfv[i / F]);
        __syncthreads();

        if (L == 3) {
            for (int i = t; i < 5 * F; i += 256) Rm[i] = sfv[i / F] * Wq[i];
            if (t < 25) {
                int oo = t / 5, k = t % 5;
                ws[WS_C + oo * 133 + cs_base[3] + k] = (k == oo) ? sfv[oo] : 0.f;
            }
            __syncthreads();
        } else {
            for (int i = t; i < 5 * O; i += 256) {
                int r = i / O, c0 = i % O;
                float v = Rm[r * O + c0] * sfv[c0];
                Cm[i] = v;
                ws[WS_C + r * 133 + cs_base[L] + c0] = v;
            }
            __syncthreads();
            for (int i = t; i < 5 * F; i += 256) {
                int r = i / F, c0 = i % F;
                float acc = 0.f;
                #pragma unroll 8
                for (int j = 0; j < O; ++j) acc += Cm[r * O + j] * Wq[j * F + c0];
                Rn[i] = acc;
            }
            __syncthreads();
            if (L == 0) {
                for (int i = t; i < 80; i += 256) ws[WS_TLIN + i] = Rn[i];
            } else {
                for (int i = t; i < 5 * F; i += 256) Rm[i] = Rn[i];
                __syncthreads();
            }
        }
    }
}

// ---- k_fin: one tiny block, all s-dependent finalize ----
__global__ void __launch_bounds__(256) k_finalize(float* __restrict__ ws) {
    __shared__ float bi[133];
    const int t = threadIdx.x;
    const float am = __uint_as_float(((const unsigned*)ws)[WS_ABS]);
    const float s = fmaxf(am / NLEV, QEPS);
    const float inv_s = 1.0f / s;

    if (t < 133) bi[t] = clipr(ws[WS_BPRE + t] * inv_s);
    __syncthreads();
    if (t < 80) ws[WS_FIN + 1 + t] = ws[WS_TLIN + t] * s;
    if (t >= 80 && t < 240) {
        int oo = (t - 80) >> 5, lane = t & 31;
        float acc = 0.f;
        for (int j = lane; j < 133; j += 32) acc += ws[WS_C + oo * 133 + j] * bi[j];
        #pragma unroll
        for (int off = 16; off > 0; off >>= 1)
            acc += __shfl_xor(acc, off, 32);
        if (lane == 0) ws[WS_FIN + 81 + oo] = acc * s;
    }
    if (t == 0) ws[WS_FIN] = inv_s;
}

// ---- k2: minimal-prologue streaming main pass ----
__global__ void __launch_bounds__(256, 6) k2_main(const float4* __restrict__ x4,
                                                  const float* __restrict__ ws,
                                                  float4* __restrict__ out4,
                                                  int nTiles) {
    __shared__ __align__(16) float ostage[640];
    const int t = threadIdx.x;
    const int v = t & 3;
    const int lrow = t >> 2;

    const float inv_s = ws[WS_FIN];
    float Mreg[5][4], cadd[5];
    #pragma unroll
    for (int oo = 0; oo < 5; ++oo) {
        cadd[oo] = ws[WS_FIN + 81 + oo];
        #pragma unroll
        for (int j = 0; j < 4; ++j)
            Mreg[oo][j] = ws[WS_FIN + 1 + oo * 16 + v * 4 + j];
    }

    int parity = 0;
    int tile = blockIdx.x;
    float4 xv = make_float4(0.f, 0.f, 0.f, 0.f);
    if (tile < nTiles) xv = x4[(size_t)tile * 256 + t];
    for (; tile < nTiles; tile += gridDim.x, parity ^= 1) {
        const int nt = tile + gridDim.x;
        float4 xn = make_float4(0.f, 0.f, 0.f, 0.f);
        if (nt < nTiles) xn = x4[(size_t)nt * 256 + t];

        float q0 = fminf(fmaxf(rintf(xv.x * inv_s), -NLEV), NLEV);
        float q1 = fminf(fmaxf(rintf(xv.y * inv_s), -NLEV), NLEV);
        float q2 = fminf(fmaxf(rintf(xv.z * inv_s), -NLEV), NLEV);
        float q3 = fminf(fmaxf(rintf(xv.w * inv_s), -NLEV), NLEV);

        float* buf = ostage + (parity ? 320 : 0);
        float p[5];
        #pragma unroll
        for (int oo = 0; oo < 5; ++oo) {
            float acc = fmaf(q0, Mreg[oo][0],
                        fmaf(q1, Mreg[oo][1],
                        fmaf(q2, Mreg[oo][2], q3 * Mreg[oo][3])));
            acc += __shfl_xor(acc, 1, 64);
            acc += __shfl_xor(acc, 2, 64);
            p[oo] = acc;
        }
        if (v == 0) {
            #pragma unroll
            for (int oo = 0; oo < 5; ++oo) buf[lrow * 5 + oo] = p[oo] + cadd[oo];
        }
        __syncthreads();
        if (t < 80) out4[(size_t)tile * 80 + t] = ((const float4*)buf)[t];
        xv = xn;
    }
}

// ---- tail rows (only launched when B % 64 != 0) ----
__global__ void __launch_bounds__(256) k_tail(const float* __restrict__ x,
                                              const float* __restrict__ ws,
                                              float* __restrict__ out,
                                              int tailStart, int B) {
    const int r = tailStart + blockIdx.x * 256 + threadIdx.x;
    if (r >= B) return;
    const float inv_s = ws[WS_FIN];
    const float* xr = x + (size_t)r * 16;
    float q[16];
    #pragma unroll
    for (int i = 0; i < 16; ++i)
        q[i] = fminf(fmaxf(rintf(xr[i] * inv_s), -NLEV), NLEV);
    #pragma unroll
    for (int oo = 0; oo < 5; ++oo) {
        float acc = ws[WS_FIN + 81 + oo];
        #pragma unroll
        for (int i = 0; i < 16; ++i) acc = fmaf(q[i], ws[WS_FIN + 1 + oo * 16 + i], acc);
        out[(size_t)r * 5 + oo] = acc;
    }
}

extern "C" void kernel_launch(void* const* d_in, const int* in_sizes, int n_in,
                              void* d_out, int out_size, void* d_ws, size_t ws_size,
                              hipStream_t stream) {
    const float* x  = (const float*)d_in[0];
    const float* w0 = (const float*)d_in[1];
    const float* b0 = (const float*)d_in[2];
    const float* w2 = (const float*)d_in[3];
    const float* b2 = (const float*)d_in[4];
    const float* w4 = (const float*)d_in[5];
    const float* b4 = (const float*)d_in[6];
    const float* w6 = (const float*)d_in[7];
    const float* b6 = (const float*)d_in[8];
    float* ws = (float*)d_ws;

    const int B  = in_sizes[0] / 16;
    const int n4 = B * 4;        // float4 elements of x
    const int nTiles = B / 64;   // full 64-row tiles

    hipMemsetAsync(ws, 0, sizeof(unsigned), stream);  // absmax slot
    k1_absmax_compose<<<SCAN_BLOCKS + 1, 256, 0, stream>>>(
        (const float4*)x, w0, b0, w2, b2, w4, b4, w6, b6, ws, n4);
    k_finalize<<<1, 256, 0, stream>>>(ws);
    k2_main<<<2048, 256, 0, stream>>>((const float4*)x, ws, (float4*)d_out, nTiles);
    const int tailStart = nTiles * 64;
    if (tailStart < B) {
        const int nTail = B - tailStart;
        k_tail<<<(nTail + 255) / 256, 256, 0, stream>>>(
            x, ws, (float*)d_out, tailStart, B);
    }
}

// Round 9
// 41.425 us; speedup vs baseline: 2.6592x; 1.4215x over previous
//
#include <hip/hip_runtime.h>

#define NLEV 127.0f
#define QEPS 1e-8f
#define SCAN_BLOCKS 2048

// ws layout (floats):
// [0..2047]     per-block |x| partial maxima (written unconditionally each call)
// [2048..2127]  T_lin[5][16]  (s-independent composite linear map)
// [2176..2308]  bpre[133] = b/w_sf, [l0:64 | l1:32 | l2:32 | l3:5]
// [2320..2984]  C[5][133] row-major bias-coefficient matrix (incl. L3 diag)
// [3072]        inv_s
// [3073..3152]  M[5][16] (pre-scaled by s)
// [3153..3157]  c[5]
#define WS_PART 0
#define WS_TLIN 2048
#define WS_BPRE 2176
#define WS_C    2320
#define WS_FIN  3072

__device__ __forceinline__ float max4(float4 v) {
    return fmaxf(fmaxf(fabsf(v.x), fabsf(v.y)), fmaxf(fabsf(v.z), fabsf(v.w)));
}
__device__ __forceinline__ float clipr(float v) {
    return fminf(fmaxf(rintf(v), -NLEV), NLEV);
}

// ---- k1: blocks 0..SCAN_BLOCKS-1 scan |x| -> per-block partials (NO global
//      atomics — single-address atomicMax costs ~40us of serialized drain);
//      block SCAN_BLOCKS composes all s-independent weight math, overlapped ----
__global__ void __launch_bounds__(256) k1_absmax_compose(
        const float4* __restrict__ x4,
        const float* __restrict__ w0, const float* __restrict__ b0,
        const float* __restrict__ w2, const float* __restrict__ b2,
        const float* __restrict__ w4, const float* __restrict__ b4,
        const float* __restrict__ w6, const float* __restrict__ b6,
        float* __restrict__ ws, int n4) {
    const int t = threadIdx.x;

    if (blockIdx.x < SCAN_BLOCKS) {
        const int tid = blockIdx.x * 256 + t;
        const int stride = SCAN_BLOCKS * 256;
        float m[8];
        #pragma unroll
        for (int k = 0; k < 8; ++k) m[k] = 0.f;
        int i = tid;
        for (; i + 7 * stride < n4; i += 8 * stride) {
            #pragma unroll
            for (int k = 0; k < 8; ++k) m[k] = fmaxf(m[k], max4(x4[i + k * stride]));
        }
        for (; i < n4; i += stride) m[0] = fmaxf(m[0], max4(x4[i]));
        float mm = fmaxf(fmaxf(fmaxf(m[0], m[1]), fmaxf(m[2], m[3])),
                         fmaxf(fmaxf(m[4], m[5]), fmaxf(m[6], m[7])));
        #pragma unroll
        for (int off = 32; off > 0; off >>= 1)
            mm = fmaxf(mm, __shfl_down(mm, off, 64));
        __shared__ float sm[4];
        if ((t & 63) == 0) sm[t >> 6] = mm;
        __syncthreads();
        if (t == 0)
            ws[WS_PART + blockIdx.x] = fmaxf(fmaxf(sm[0], sm[1]), fmaxf(sm[2], sm[3]));
        return;
    }

    // ---- compose block (entirely s-independent), layers processed 3 -> 0 ----
    __shared__ float Wq[2048];          // max O*F = 32*64
    __shared__ float Rm[5 * 64], Rn[5 * 64], Cm[5 * 64];
    __shared__ float sfv[64];
    __shared__ unsigned rmax[64];

    const float* Wl[4] = {w0, w2, w4, w6};
    const float* Bl[4] = {b0, b2, b4, b6};
    const int Ol[4] = {64, 32, 32, 5};
    const int Fl[4] = {16, 64, 32, 32};
    const int bpre_off[4] = {0, 64, 96, 128};
    const int cs_base[4]  = {0, 64, 96, 128};

    for (int L = 3; L >= 0; --L) {
        const int O = Ol[L], F = Fl[L];
        const float* W = Wl[L];
        const float* Bb = Bl[L];
        if (t < 64) rmax[t] = 0u;
        __syncthreads();
        const int nf4 = O * F / 4, f4row = F / 4;
        for (int i = t; i < nf4; i += 256) {
            float4 wv = ((const float4*)W)[i];
            atomicMax(&rmax[i / f4row], __float_as_uint(max4(wv)));
        }
        __syncthreads();
        if (t < O) {
            float sf = fmaxf(__uint_as_float(rmax[t]) / NLEV, QEPS);
            sfv[t] = sf;
            ws[WS_BPRE + bpre_off[L] + t] = Bb[t] / sf;
        }
        __syncthreads();
        for (int i = t; i < O * F; i += 256)
            Wq[i] = clipr(W[i] / sfv[i / F]);
        __syncthreads();

        if (L == 3) {
            for (int i = t; i < 5 * F; i += 256) Rm[i] = sfv[i / F] * Wq[i];
            if (t < 25) {
                int oo = t / 5, k = t % 5;
                ws[WS_C + oo * 133 + cs_base[3] + k] = (k == oo) ? sfv[oo] : 0.f;
            }
            __syncthreads();
        } else {
            for (int i = t; i < 5 * O; i += 256) {
                int r = i / O, c0 = i % O;
                float v = Rm[r * O + c0] * sfv[c0];
                Cm[i] = v;
                ws[WS_C + r * 133 + cs_base[L] + c0] = v;
            }
            __syncthreads();
            for (int i = t; i < 5 * F; i += 256) {
                int r = i / F, c0 = i % F;
                float acc = 0.f;
                #pragma unroll 8
                for (int j = 0; j < O; ++j) acc += Cm[r * O + j] * Wq[j * F + c0];
                Rn[i] = acc;
            }
            __syncthreads();
            if (L == 0) {
                for (int i = t; i < 80; i += 256) ws[WS_TLIN + i] = Rn[i];
            } else {
                for (int i = t; i < 5 * F; i += 256) Rm[i] = Rn[i];
                __syncthreads();
            }
        }
    }
}

// ---- k_fin: one tiny block — reduce partials -> s, then all s-dependent math ----
__global__ void __launch_bounds__(256) k_finalize(float* __restrict__ ws) {
    __shared__ float bi[133];
    __shared__ float red[4];
    __shared__ float s_sh;
    const int t = threadIdx.x;

    float pm = 0.f;
    for (int i = t; i < SCAN_BLOCKS; i += 256) pm = fmaxf(pm, ws[WS_PART + i]);
    #pragma unroll
    for (int off = 32; off > 0; off >>= 1)
        pm = fmaxf(pm, __shfl_down(pm, off, 64));
    if ((t & 63) == 0) red[t >> 6] = pm;
    __syncthreads();
    if (t == 0) {
        float am = fmaxf(fmaxf(red[0], red[1]), fmaxf(red[2], red[3]));
        s_sh = fmaxf(am / NLEV, QEPS);
    }
    __syncthreads();
    const float s = s_sh;
    const float inv_s = 1.0f / s;

    if (t < 133) bi[t] = clipr(ws[WS_BPRE + t] * inv_s);
    __syncthreads();
    if (t < 80) ws[WS_FIN + 1 + t] = ws[WS_TLIN + t] * s;
    if (t >= 80 && t < 240) {
        int oo = (t - 80) >> 5, lane = t & 31;
        float acc = 0.f;
        for (int j = lane; j < 133; j += 32) acc += ws[WS_C + oo * 133 + j] * bi[j];
        #pragma unroll
        for (int off = 16; off > 0; off >>= 1)
            acc += __shfl_xor(acc, off, 32);
        if (lane == 0) ws[WS_FIN + 81 + oo] = acc * s;
    }
    if (t == 0) ws[WS_FIN] = inv_s;
}

// ---- k2: minimal-prologue streaming main pass (R8 version, measured ~10us) ----
__global__ void __launch_bounds__(256, 6) k2_main(const float4* __restrict__ x4,
                                                  const float* __restrict__ ws,
                                                  float4* __restrict__ out4,
                                                  int nTiles) {
    __shared__ __align__(16) float ostage[640];
    const int t = threadIdx.x;
    const int v = t & 3;
    const int lrow = t >> 2;

    const float inv_s = ws[WS_FIN];
    float Mreg[5][4], cadd[5];
    #pragma unroll
    for (int oo = 0; oo < 5; ++oo) {
        cadd[oo] = ws[WS_FIN + 81 + oo];
        #pragma unroll
        for (int j = 0; j < 4; ++j)
            Mreg[oo][j] = ws[WS_FIN + 1 + oo * 16 + v * 4 + j];
    }

    int parity = 0;
    int tile = blockIdx.x;
    float4 xv = make_float4(0.f, 0.f, 0.f, 0.f);
    if (tile < nTiles) xv = x4[(size_t)tile * 256 + t];
    for (; tile < nTiles; tile += gridDim.x, parity ^= 1) {
        const int nt = tile + gridDim.x;
        float4 xn = make_float4(0.f, 0.f, 0.f, 0.f);
        if (nt < nTiles) xn = x4[(size_t)nt * 256 + t];

        float q0 = fminf(fmaxf(rintf(xv.x * inv_s), -NLEV), NLEV);
        float q1 = fminf(fmaxf(rintf(xv.y * inv_s), -NLEV), NLEV);
        float q2 = fminf(fmaxf(rintf(xv.z * inv_s), -NLEV), NLEV);
        float q3 = fminf(fmaxf(rintf(xv.w * inv_s), -NLEV), NLEV);

        float* buf = ostage + (parity ? 320 : 0);
        float p[5];
        #pragma unroll
        for (int oo = 0; oo < 5; ++oo) {
            float acc = fmaf(q0, Mreg[oo][0],
                        fmaf(q1, Mreg[oo][1],
                        fmaf(q2, Mreg[oo][2], q3 * Mreg[oo][3])));
            acc += __shfl_xor(acc, 1, 64);
            acc += __shfl_xor(acc, 2, 64);
            p[oo] = acc;
        }
        if (v == 0) {
            #pragma unroll
            for (int oo = 0; oo < 5; ++oo) buf[lrow * 5 + oo] = p[oo] + cadd[oo];
        }
        __syncthreads();
        if (t < 80) out4[(size_t)tile * 80 + t] = ((const float4*)buf)[t];
        xv = xn;
    }
}

// ---- tail rows (only launched when B % 64 != 0) ----
__global__ void __launch_bounds__(256) k_tail(const float* __restrict__ x,
                                              const float* __restrict__ ws,
                                              float* __restrict__ out,
                                              int tailStart, int B) {
    const int r = tailStart + blockIdx.x * 256 + threadIdx.x;
    if (r >= B) return;
    const float inv_s = ws[WS_FIN];
    const float* xr = x + (size_t)r * 16;
    float q[16];
    #pragma unroll
    for (int i = 0; i < 16; ++i)
        q[i] = fminf(fmaxf(rintf(xr[i] * inv_s), -NLEV), NLEV);
    #pragma unroll
    for (int oo = 0; oo < 5; ++oo) {
        float acc = ws[WS_FIN + 81 + oo];
        #pragma unroll
        for (int i = 0; i < 16; ++i) acc = fmaf(q[i], ws[WS_FIN + 1 + oo * 16 + i], acc);
        out[(size_t)r * 5 + oo] = acc;
    }
}

extern "C" void kernel_launch(void* const* d_in, const int* in_sizes, int n_in,
                              void* d_out, int out_size, void* d_ws, size_t ws_size,
                              hipStream_t stream) {
    const float* x  = (const float*)d_in[0];
    const float* w0 = (const float*)d_in[1];
    const float* b0 = (const float*)d_in[2];
    const float* w2 = (const float*)d_in[3];
    const float* b2 = (const float*)d_in[4];
    const float* w4 = (const float*)d_in[5];
    const float* b4 = (const float*)d_in[6];
    const float* w6 = (const float*)d_in[7];
    const float* b6 = (const float*)d_in[8];
    float* ws = (float*)d_ws;

    const int B  = in_sizes[0] / 16;
    const int n4 = B * 4;        // float4 elements of x
    const int nTiles = B / 64;   // full 64-row tiles

    k1_absmax_compose<<<SCAN_BLOCKS + 1, 256, 0, stream>>>(
        (const float4*)x, w0, b0, w2, b2, w4, b4, w6, b6, ws, n4);
    k_finalize<<<1, 256, 0, stream>>>(ws);
    k2_main<<<2048, 256, 0, stream>>>((const float4*)x, ws, (float4*)d_out, nTiles);
    const int tailStart = nTiles * 64;
    if (tailStart < B) {
        const int nTail = B - tailStart;
        k_tail<<<(nTail + 255) / 256, 256, 0, stream>>>(
            x, ws, (float*)d_out, tailStart, B);
    }
}